// Round 3
// baseline (37183.615 us; speedup 1.0000x reference)
//
#include <hip/hip_runtime.h>
#include <hip/hip_bf16.h>
#include <math.h>

// Problem dims
#define BB 8
#define TT 16
#define HH 112
#define WW 112
#define CC 3
#define FF 16
#define HP 56
#define WP 56
#define HO 54
#define WO 54
#define NC 6

// ws layout (floats)
#define POOLED_ELEMS (128*56*56*16)   // 6,422,528
#define HSTATE_ELEMS (8*54*54*16)     // 373,248
#define WPACK_ELEMS  (16*9*16*8)      // 18,432  [ch][tap][ci][wk i,f,g,o | wr i,f,g,o]
#define NPIX (BB*HO*WO)               // 23328

__device__ __forceinline__ float hsig(float x) {
    return fminf(fmaxf(0.2f*x + 0.5f, 0.0f), 1.0f);
}

// Kernel 0: repack LSTM weights from [3,3,16,64] (gate-major last dim) into
// per-channel contiguous slices: wpack[ch][tap][ci][slot], slot 0..3 = wk gates
// i,f,g,o ; slot 4..7 = wr gates. One channel slice = 1152 floats = 4.6 KB.
__global__ __launch_bounds__(256) void repack_kernel(
    const float* __restrict__ wk, const float* __restrict__ wr,
    float* __restrict__ wpack)
{
    int i = blockIdx.x * 256 + threadIdx.x;        // 72*256 = 18432 exact
    int slot = i & 7;
    int ci   = (i >> 3) & 15;
    int tap  = (i >> 7) % 9;
    int ch   = i / (9*16*8);
    int gate = slot & 3;
    const float* src = (slot & 4) ? wr : wk;
    wpack[i] = src[tap*16*64 + ci*64 + gate*16 + ch];
}

// Kernel 1: fused 7x7 SAME conv (3->16) + bias + relu + 2x2 maxpool.
__global__ __launch_bounds__(256) void conv_pool_kernel(
    const float* __restrict__ x,      // [128,112,112,3]
    const float* __restrict__ cw,     // [7,7,3,16]
    const float* __restrict__ cb,     // [16]
    float* __restrict__ pooled)       // [128,56,56,16]
{
    int idx = blockIdx.x * 256 + threadIdx.x;   // 128*56*56 = 401408 = 1568*256 exact
    int fr = idx / (HP*WP);
    int r  = idx % (HP*WP);
    int ph = r / WP, pw = r % WP;

    const float* xf = x + (size_t)fr * HH * WW * CC;

    float best[16];
    #pragma unroll
    for (int i = 0; i < 16; ++i) best[i] = -1e30f;

    for (int py = 0; py < 2; ++py) {
        for (int px = 0; px < 2; ++px) {
            int oh = 2*ph + py, ow = 2*pw + px;
            float acc[16];
            #pragma unroll
            for (int i = 0; i < 16; ++i) acc[i] = cb[i];
            for (int ky = 0; ky < 7; ++ky) {
                int ih = oh - 3 + ky;
                if (ih < 0 || ih >= HH) continue;
                for (int kx = 0; kx < 7; ++kx) {
                    int iw = ow - 3 + kx;
                    if (iw < 0 || iw >= WW) continue;
                    const float* xp = xf + ((size_t)ih * WW + iw) * CC;
                    const float* wp = cw + ((ky*7 + kx) * CC) * 16;
                    #pragma unroll
                    for (int ci = 0; ci < 3; ++ci) {
                        float a = xp[ci];
                        #pragma unroll
                        for (int fo = 0; fo < 16; ++fo)
                            acc[fo] += a * wp[ci*16 + fo];
                    }
                }
            }
            #pragma unroll
            for (int i = 0; i < 16; ++i) best[i] = fmaxf(best[i], acc[i]);
        }
    }

    float4* op = (float4*)(pooled + (size_t)idx * 16);
    #pragma unroll
    for (int v = 0; v < 4; ++v) {
        float4 o;
        o.x = fmaxf(best[v*4+0], 0.0f);
        o.y = fmaxf(best[v*4+1], 0.0f);
        o.z = fmaxf(best[v*4+2], 0.0f);
        o.w = fmaxf(best[v*4+3], 0.0f);
        op[v] = o;
    }
}

// Kernel 2: one ConvLSTM time step, fully fused.
// Thread = 2 adjacent output pixels (same row) x ONE feature channel.
// Weights come from LDS (staged once per block), read at wave-uniform
// addresses -> conflict-free broadcast ds_read_b128.
// Per ky: a-pass (4 shared columns, wk) then h-pass (4 columns, wr) to keep
// the live activation set at 64 floats.
// Grid: 46 x 16 blocks.
__global__ __launch_bounds__(256) void lstm_step_kernel(
    const float* __restrict__ pooled,   // [128,56,56,16]
    const float* __restrict__ h_in,     // [8,54,54,16]
    float* __restrict__ h_out,          // [8,54,54,16]
    float* __restrict__ cst,            // [8,54,54,16]
    const float* __restrict__ wpack,    // [16][9][16][8]
    const float* __restrict__ bias,     // [64]
    int t)
{
    int ch = blockIdx.y;                // wave-uniform channel

    // Stage this channel's weight slice into LDS (288 float4 = 4608 B).
    __shared__ float wlds[1152];
    {
        const float4* src = (const float4*)(wpack + ch * 1152);
        float4* dst = (float4*)wlds;
        for (int i = threadIdx.x; i < 288; i += 256) dst[i] = src[i];
    }
    __syncthreads();

    const int NT = BB * HO * (WO/2);    // 8*54*27 = 11664 threads of work
    int idx = blockIdx.x * 256 + threadIdx.x;
    if (idx < NT) {
        int b   = idx / (HO*27);
        int r   = idx % (HO*27);
        int oh  = r / 27;
        int ow0 = (r % 27) * 2;         // pixels ow0, ow0+1

        float acc[8];                   // [pixel][gate i,f,g,o]
        #pragma unroll
        for (int i = 0; i < 8; ++i) acc[i] = 0.0f;

        const float* pf = pooled + (size_t)(b*TT + t) * HP * WP * 16;
        const float* hb = h_in + (size_t)b * HO * WO * 16;
        const float4* wl = (const float4*)wlds;

        float cols[4][16];

        #pragma unroll
        for (int ky = 0; ky < 3; ++ky) {
            // ---- A pass: pooled frame, VALID conv (always in range) ----
            int ph = oh + ky;           // 0..55
            #pragma unroll
            for (int c = 0; c < 4; ++c) {
                const float4* pp = (const float4*)(pf + ((size_t)ph * WP + (ow0 + c)) * 16);
                #pragma unroll
                for (int v = 0; v < 4; ++v) {
                    float4 t4 = pp[v];
                    cols[c][v*4+0] = t4.x; cols[c][v*4+1] = t4.y;
                    cols[c][v*4+2] = t4.z; cols[c][v*4+3] = t4.w;
                }
            }
            #pragma unroll
            for (int kx = 0; kx < 3; ++kx) {
                #pragma unroll
                for (int ci = 0; ci < 16; ++ci) {
                    float4 w4 = wl[((ky*3 + kx)*16 + ci)*2 + 0];   // wk, broadcast
                    float a0 = cols[kx][ci], a1 = cols[kx+1][ci];
                    acc[0] += a0*w4.x; acc[1] += a0*w4.y; acc[2] += a0*w4.z; acc[3] += a0*w4.w;
                    acc[4] += a1*w4.x; acc[5] += a1*w4.y; acc[6] += a1*w4.z; acc[7] += a1*w4.w;
                }
            }
            // ---- H pass: recurrent state, SAME conv (pad with zeros) ----
            int hy = oh + ky - 1;
            bool rowv = (hy >= 0 && hy < HO);
            #pragma unroll
            for (int c = 0; c < 4; ++c) {
                int hx = ow0 + c - 1;
                bool v4ok = rowv && (hx >= 0) && (hx < WO);
                const float4* hp = (const float4*)(hb + ((size_t)hy * WO + hx) * 16);
                #pragma unroll
                for (int v = 0; v < 4; ++v) {
                    float4 t4 = v4ok ? hp[v] : make_float4(0.f,0.f,0.f,0.f);
                    cols[c][v*4+0] = t4.x; cols[c][v*4+1] = t4.y;
                    cols[c][v*4+2] = t4.z; cols[c][v*4+3] = t4.w;
                }
            }
            #pragma unroll
            for (int kx = 0; kx < 3; ++kx) {
                #pragma unroll
                for (int ci = 0; ci < 16; ++ci) {
                    float4 w4 = wl[((ky*3 + kx)*16 + ci)*2 + 1];   // wr, broadcast
                    float h0 = cols[kx][ci], h1 = cols[kx+1][ci];
                    acc[0] += h0*w4.x; acc[1] += h0*w4.y; acc[2] += h0*w4.z; acc[3] += h0*w4.w;
                    acc[4] += h1*w4.x; acc[5] += h1*w4.y; acc[6] += h1*w4.z; acc[7] += h1*w4.w;
                }
            }
        }

        float b_i = bias[ 0 + ch], b_f = bias[16 + ch];
        float b_g = bias[32 + ch], b_o = bias[48 + ch];
        #pragma unroll
        for (int p = 0; p < 2; ++p) {
            float iv = hsig(acc[p*4+0] + b_i);
            float fv = hsig(acc[p*4+1] + b_f);
            float gv = tanhf(acc[p*4+2] + b_g);
            float ov = hsig(acc[p*4+3] + b_o);
            size_t base = (((size_t)b * HO + oh) * WO + (ow0 + p)) * 16 + ch;
            float cold = cst[base];
            float cn = fv * cold + iv * gv;
            cst[base] = cn;
            h_out[base] = ov * tanhf(cn);
        }
    }
}

// Kernel 3: spatial mean over 54x54 -> dense(16->6) -> softmax. One block per b.
__global__ __launch_bounds__(256) void head_kernel(
    const float* __restrict__ h,    // [8,54,54,16]
    const float* __restrict__ dw,   // [16,6]
    const float* __restrict__ db,   // [6]
    float* __restrict__ out)        // [8,6]
{
    int b = blockIdx.x;
    int tid = threadIdx.x;
    const float* hb = h + (size_t)b * HO * WO * 16;
    float s = 0.0f;
    for (int i = tid; i < HO*WO*16; i += 256) s += hb[i];  // stride 256 == 0 mod 16 -> fixed ch per thread
    __shared__ float red[256];
    red[tid] = s;
    __syncthreads();
    for (int st = 128; st >= 16; st >>= 1) {
        if (tid < st) red[tid] += red[tid + st];
        __syncthreads();
    }
    __shared__ float logits[8];
    if (tid < NC) {
        float l = db[tid];
        #pragma unroll
        for (int ch = 0; ch < 16; ++ch)
            l += (red[ch] * (1.0f/2916.0f)) * dw[ch*NC + tid];
        logits[tid] = l;
    }
    __syncthreads();
    if (tid < NC) {
        float m = -1e30f;
        for (int k = 0; k < NC; ++k) m = fmaxf(m, logits[k]);
        float e = expf(logits[tid] - m);
        float d = 0.0f;
        for (int k = 0; k < NC; ++k) d += expf(logits[k] - m);
        out[b*NC + tid] = e / d;
    }
}

extern "C" void kernel_launch(void* const* d_in, const int* in_sizes, int n_in,
                              void* d_out, int out_size, void* d_ws, size_t ws_size,
                              hipStream_t stream) {
    const float* x      = (const float*)d_in[0];
    const float* conv_w = (const float*)d_in[1];
    const float* conv_b = (const float*)d_in[2];
    const float* wk     = (const float*)d_in[3];
    const float* wr     = (const float*)d_in[4];
    const float* bias   = (const float*)d_in[5];
    const float* dw     = (const float*)d_in[6];
    const float* db     = (const float*)d_in[7];
    float* out = (float*)d_out;

    float* ws     = (float*)d_ws;
    float* pooled = ws;
    float* hA     = pooled + POOLED_ELEMS;
    float* hB     = hA + HSTATE_ELEMS;
    float* cbuf   = hB + HSTATE_ELEMS;
    float* wpack  = cbuf + HSTATE_ELEMS;

    // h0 = 0, c0 = 0 (ws is poisoned before every launch)
    hipMemsetAsync(hA,   0, HSTATE_ELEMS * sizeof(float), stream);
    hipMemsetAsync(cbuf, 0, HSTATE_ELEMS * sizeof(float), stream);

    repack_kernel<<<dim3(72), dim3(256), 0, stream>>>(wk, wr, wpack);
    conv_pool_kernel<<<dim3(1568), dim3(256), 0, stream>>>(x, conv_w, conv_b, pooled);

    for (int t = 0; t < TT; ++t) {
        const float* hin  = (t & 1) ? hB : hA;
        float*       hout = (t & 1) ? hA : hB;
        lstm_step_kernel<<<dim3(46, 16), dim3(256), 0, stream>>>(
            pooled, hin, hout, cbuf, wpack, bias, t);
    }
    // t=15 (odd) wrote hA
    head_kernel<<<dim3(8), dim3(256), 0, stream>>>(hA, dw, db, out);
}

// Round 4
// 18499.020 us; speedup vs baseline: 2.0100x; 2.0100x over previous
//
#include <hip/hip_runtime.h>
#include <hip/hip_bf16.h>
#include <math.h>

// Problem dims
#define BB 8
#define TT 16
#define HH 112
#define WW 112
#define CC 3
#define FF 16
#define HP 56
#define WP 56
#define HO 54
#define WO 54
#define NC 6

// ws layout (floats)
#define POOLED_ELEMS (128*56*56*16)   // 6,422,528
#define HSTATE_ELEMS (8*54*54*16)     // 373,248
#define WPACK_ELEMS  (16*9*16*8)      // 18,432  [ch][tap][ci][wk i,f,g,o | wr i,f,g,o]
#define NPIX (BB*HO*WO)               // 23328

__device__ __forceinline__ float hsig(float x) {
    return fminf(fmaxf(0.2f*x + 0.5f, 0.0f), 1.0f);
}

// Kernel 0: repack LSTM weights from [3,3,16,64] (gate-major last dim) into
// per-channel contiguous slices: wpack[ch][tap][ci][slot], slot 0..3 = wk gates
// i,f,g,o ; slot 4..7 = wr gates. One channel slice = 1152 floats = 4.6 KB.
__global__ __launch_bounds__(256) void repack_kernel(
    const float* __restrict__ wk, const float* __restrict__ wr,
    float* __restrict__ wpack)
{
    int i = blockIdx.x * 256 + threadIdx.x;        // 72*256 = 18432 exact
    int slot = i & 7;
    int ci   = (i >> 3) & 15;
    int tap  = (i >> 7) % 9;
    int ch   = i / (9*16*8);
    int gate = slot & 3;
    const float* src = (slot & 4) ? wr : wk;
    wpack[i] = src[tap*16*64 + ci*64 + gate*16 + ch];
}

// Kernel 1: fused 7x7 SAME conv (3->16) + bias + relu + 2x2 maxpool.
__global__ __launch_bounds__(256) void conv_pool_kernel(
    const float* __restrict__ x,      // [128,112,112,3]
    const float* __restrict__ cw,     // [7,7,3,16]
    const float* __restrict__ cb,     // [16]
    float* __restrict__ pooled)       // [128,56,56,16]
{
    int idx = blockIdx.x * 256 + threadIdx.x;   // 128*56*56 = 401408 = 1568*256 exact
    int fr = idx / (HP*WP);
    int r  = idx % (HP*WP);
    int ph = r / WP, pw = r % WP;

    const float* xf = x + (size_t)fr * HH * WW * CC;

    float best[16];
    #pragma unroll
    for (int i = 0; i < 16; ++i) best[i] = -1e30f;

    for (int py = 0; py < 2; ++py) {
        for (int px = 0; px < 2; ++px) {
            int oh = 2*ph + py, ow = 2*pw + px;
            float acc[16];
            #pragma unroll
            for (int i = 0; i < 16; ++i) acc[i] = cb[i];
            for (int ky = 0; ky < 7; ++ky) {
                int ih = oh - 3 + ky;
                if (ih < 0 || ih >= HH) continue;
                for (int kx = 0; kx < 7; ++kx) {
                    int iw = ow - 3 + kx;
                    if (iw < 0 || iw >= WW) continue;
                    const float* xp = xf + ((size_t)ih * WW + iw) * CC;
                    const float* wp = cw + ((ky*7 + kx) * CC) * 16;
                    #pragma unroll
                    for (int ci = 0; ci < 3; ++ci) {
                        float a = xp[ci];
                        #pragma unroll
                        for (int fo = 0; fo < 16; ++fo)
                            acc[fo] += a * wp[ci*16 + fo];
                    }
                }
            }
            #pragma unroll
            for (int i = 0; i < 16; ++i) best[i] = fmaxf(best[i], acc[i]);
        }
    }

    float4* op = (float4*)(pooled + (size_t)idx * 16);
    #pragma unroll
    for (int v = 0; v < 4; ++v) {
        float4 o;
        o.x = fmaxf(best[v*4+0], 0.0f);
        o.y = fmaxf(best[v*4+1], 0.0f);
        o.z = fmaxf(best[v*4+2], 0.0f);
        o.w = fmaxf(best[v*4+3], 0.0f);
        op[v] = o;
    }
}

// Kernel 2: one ConvLSTM time step, fully fused.
// Thread = one output pixel x ONE feature channel (R1's proven 64-VGPR body).
// Weights: per-block LDS stage of the 4.6 KB per-channel slice; inner-loop
// reads are wave-uniform addresses -> conflict-free broadcast ds_read_b128.
// Grid: 92 x 16 = 1472 blocks.
__global__ __launch_bounds__(256) void lstm_step_kernel(
    const float* __restrict__ pooled,   // [128,56,56,16]
    const float* __restrict__ h_in,     // [8,54,54,16]
    float* __restrict__ h_out,          // [8,54,54,16]
    float* __restrict__ cst,            // [8,54,54,16]
    const float* __restrict__ wpack,    // [16][9][16][8]
    const float* __restrict__ bias,     // [64]
    int t)
{
    int ch = blockIdx.y;                // wave-uniform channel

    // Stage this channel's weight slice into LDS (288 float4 = 4608 B).
    __shared__ float4 wlds[288];
    {
        const float4* src = (const float4*)(wpack + ch * 1152);
        for (int i = threadIdx.x; i < 288; i += 256) wlds[i] = src[i];
    }
    __syncthreads();                    // before any thread can exit

    int pix = blockIdx.x * 256 + threadIdx.x;
    if (pix >= NPIX) return;

    int b  = pix / (HO*WO);
    int r  = pix % (HO*WO);
    int oh = r / WO, ow = r % WO;

    float acc0 = 0.f, acc1 = 0.f, acc2 = 0.f, acc3 = 0.f;

    const float* pf = pooled + (size_t)(b*TT + t) * HP * WP * 16;
    const float* hb = h_in + (size_t)b * HO * WO * 16;

    for (int ky = 0; ky < 3; ++ky) {
        int ph = oh + ky;           // VALID: always in range 0..55
        int hy = oh + ky - 1;       // SAME pad for recurrent conv
        for (int kx = 0; kx < 3; ++kx) {
            int pw = ow + kx;
            int hx = ow + kx - 1;
            bool hv = (hy >= 0 && hy < HO && hx >= 0 && hx < WO);

            const float4* pp = (const float4*)(pf + ((size_t)ph * WP + pw) * 16);
            const float4* hp = (const float4*)(hb + ((size_t)hy * WO + hx) * 16);

            float a[16], h[16];
            #pragma unroll
            for (int v = 0; v < 4; ++v) {
                float4 av = pp[v];
                a[v*4+0] = av.x; a[v*4+1] = av.y; a[v*4+2] = av.z; a[v*4+3] = av.w;
                float4 hv4 = hv ? hp[v] : make_float4(0.f, 0.f, 0.f, 0.f);
                h[v*4+0] = hv4.x; h[v*4+1] = hv4.y; h[v*4+2] = hv4.z; h[v*4+3] = hv4.w;
            }

            const float4* wl = &wlds[((ky*3 + kx) * 16) * 2];
            #pragma unroll
            for (int ci = 0; ci < 16; ++ci) {
                float4 wk4 = wl[ci*2 + 0];   // broadcast (all lanes same addr)
                float4 wr4 = wl[ci*2 + 1];
                float av = a[ci], hvv = h[ci];
                acc0 += av * wk4.x + hvv * wr4.x;
                acc1 += av * wk4.y + hvv * wr4.y;
                acc2 += av * wk4.z + hvv * wr4.z;
                acc3 += av * wk4.w + hvv * wr4.w;
            }
        }
    }

    float iv = hsig(acc0 + bias[ 0 + ch]);
    float fv = hsig(acc1 + bias[16 + ch]);
    float gv = tanhf(acc2 + bias[32 + ch]);
    float ov = hsig(acc3 + bias[48 + ch]);

    size_t base = (size_t)pix * 16 + ch;
    float cold = cst[base];
    float cn = fv * cold + iv * gv;
    cst[base] = cn;
    h_out[base] = ov * tanhf(cn);
}

// Kernel 3: spatial mean over 54x54 -> dense(16->6) -> softmax. One block per b.
__global__ __launch_bounds__(256) void head_kernel(
    const float* __restrict__ h,    // [8,54,54,16]
    const float* __restrict__ dw,   // [16,6]
    const float* __restrict__ db,   // [6]
    float* __restrict__ out)        // [8,6]
{
    int b = blockIdx.x;
    int tid = threadIdx.x;
    const float* hb = h + (size_t)b * HO * WO * 16;
    float s = 0.0f;
    for (int i = tid; i < HO*WO*16; i += 256) s += hb[i];  // stride 256 == 0 mod 16 -> fixed ch per thread
    __shared__ float red[256];
    red[tid] = s;
    __syncthreads();
    for (int st = 128; st >= 16; st >>= 1) {
        if (tid < st) red[tid] += red[tid + st];
        __syncthreads();
    }
    __shared__ float logits[8];
    if (tid < NC) {
        float l = db[tid];
        #pragma unroll
        for (int ch = 0; ch < 16; ++ch)
            l += (red[ch] * (1.0f/2916.0f)) * dw[ch*NC + tid];
        logits[tid] = l;
    }
    __syncthreads();
    if (tid < NC) {
        float m = -1e30f;
        for (int k = 0; k < NC; ++k) m = fmaxf(m, logits[k]);
        float e = expf(logits[tid] - m);
        float d = 0.0f;
        for (int k = 0; k < NC; ++k) d += expf(logits[k] - m);
        out[b*NC + tid] = e / d;
    }
}

extern "C" void kernel_launch(void* const* d_in, const int* in_sizes, int n_in,
                              void* d_out, int out_size, void* d_ws, size_t ws_size,
                              hipStream_t stream) {
    const float* x      = (const float*)d_in[0];
    const float* conv_w = (const float*)d_in[1];
    const float* conv_b = (const float*)d_in[2];
    const float* wk     = (const float*)d_in[3];
    const float* wr     = (const float*)d_in[4];
    const float* bias   = (const float*)d_in[5];
    const float* dw     = (const float*)d_in[6];
    const float* db     = (const float*)d_in[7];
    float* out = (float*)d_out;

    float* ws     = (float*)d_ws;
    float* pooled = ws;
    float* hA     = pooled + POOLED_ELEMS;
    float* hB     = hA + HSTATE_ELEMS;
    float* cbuf   = hB + HSTATE_ELEMS;
    float* wpack  = cbuf + HSTATE_ELEMS;

    // h0 = 0, c0 = 0 (ws is poisoned before every launch)
    hipMemsetAsync(hA,   0, HSTATE_ELEMS * sizeof(float), stream);
    hipMemsetAsync(cbuf, 0, HSTATE_ELEMS * sizeof(float), stream);

    repack_kernel<<<dim3(72), dim3(256), 0, stream>>>(wk, wr, wpack);
    conv_pool_kernel<<<dim3(1568), dim3(256), 0, stream>>>(x, conv_w, conv_b, pooled);

    for (int t = 0; t < TT; ++t) {
        const float* hin  = (t & 1) ? hB : hA;
        float*       hout = (t & 1) ? hA : hB;
        lstm_step_kernel<<<dim3(92, 16), dim3(256), 0, stream>>>(
            pooled, hin, hout, cbuf, wpack, bias, t);
    }
    // t=15 (odd) wrote hA
    head_kernel<<<dim3(8), dim3(256), 0, stream>>>(hA, dw, db, out);
}

// Round 5
// 1098.504 us; speedup vs baseline: 33.8493x; 16.8402x over previous
//
#include <hip/hip_runtime.h>
#include <hip/hip_bf16.h>
#include <math.h>

// Problem dims
#define BB 8
#define TT 16
#define HH 112
#define WW 112
#define CC 3
#define FF 16
#define HP 56
#define WP 56
#define HO 54
#define WO 54
#define NC 6

// ws layout (floats)
#define POOLED_ELEMS (128*56*56*16)   // 6,422,528
#define HSTATE_ELEMS (8*54*54*16)     // 373,248
#define WPACK_ELEMS  (16*9*16*8)      // 18,432  [ch][tap][ci][wk i,f,g,o | wr i,f,g,o]
#define NPIX (BB*HO*WO)               // 23328

__device__ __forceinline__ float hsig(float x) {
    return fminf(fmaxf(0.2f*x + 0.5f, 0.0f), 1.0f);
}

// Kernel 0: repack LSTM weights from [3,3,16,64] (gate-major last dim) into
// per-channel contiguous slices: wpack[ch][tap][ci][slot], slot 0..3 = wk gates
// i,f,g,o ; slot 4..7 = wr gates. One channel slice = 1152 floats = 4.6 KB.
__global__ __launch_bounds__(256) void repack_kernel(
    const float* __restrict__ wk, const float* __restrict__ wr,
    float* __restrict__ wpack)
{
    int i = blockIdx.x * 256 + threadIdx.x;        // 72*256 = 18432 exact
    int slot = i & 7;
    int ci   = (i >> 3) & 15;
    int tap  = (i >> 7) % 9;
    int ch   = i / (9*16*8);
    int gate = slot & 3;
    const float* src = (slot & 4) ? wr : wk;
    wpack[i] = src[tap*16*64 + ci*64 + gate*16 + ch];
}

// Kernel 1: fused 7x7 SAME conv (3->16) + bias + relu + 2x2 maxpool.
__global__ __launch_bounds__(256) void conv_pool_kernel(
    const float* __restrict__ x,      // [128,112,112,3]
    const float* __restrict__ cw,     // [7,7,3,16]
    const float* __restrict__ cb,     // [16]
    float* __restrict__ pooled)       // [128,56,56,16]
{
    int idx = blockIdx.x * 256 + threadIdx.x;   // 128*56*56 = 401408 = 1568*256 exact
    int fr = idx / (HP*WP);
    int r  = idx % (HP*WP);
    int ph = r / WP, pw = r % WP;

    const float* xf = x + (size_t)fr * HH * WW * CC;

    float best[16];
    #pragma unroll
    for (int i = 0; i < 16; ++i) best[i] = -1e30f;

    for (int py = 0; py < 2; ++py) {
        for (int px = 0; px < 2; ++px) {
            int oh = 2*ph + py, ow = 2*pw + px;
            float acc[16];
            #pragma unroll
            for (int i = 0; i < 16; ++i) acc[i] = cb[i];
            for (int ky = 0; ky < 7; ++ky) {
                int ih = oh - 3 + ky;
                if (ih < 0 || ih >= HH) continue;
                for (int kx = 0; kx < 7; ++kx) {
                    int iw = ow - 3 + kx;
                    if (iw < 0 || iw >= WW) continue;
                    const float* xp = xf + ((size_t)ih * WW + iw) * CC;
                    const float* wp = cw + ((ky*7 + kx) * CC) * 16;
                    #pragma unroll
                    for (int ci = 0; ci < 3; ++ci) {
                        float a = xp[ci];
                        #pragma unroll
                        for (int fo = 0; fo < 16; ++fo)
                            acc[fo] += a * wp[ci*16 + fo];
                    }
                }
            }
            #pragma unroll
            for (int i = 0; i < 16; ++i) best[i] = fmaxf(best[i], acc[i]);
        }
    }

    float4* op = (float4*)(pooled + (size_t)idx * 16);
    #pragma unroll
    for (int v = 0; v < 4; ++v) {
        float4 o;
        o.x = fmaxf(best[v*4+0], 0.0f);
        o.y = fmaxf(best[v*4+1], 0.0f);
        o.z = fmaxf(best[v*4+2], 0.0f);
        o.w = fmaxf(best[v*4+3], 0.0f);
        op[v] = o;
    }
}

// Kernel 2: one ConvLSTM time step, fully fused.
// Thread = one output pixel x ONE feature channel.
// Weights: per-block LDS stage of the 4.6 KB per-channel slice; inner-loop
// reads are wave-uniform addresses -> conflict-free broadcast ds_read_b128.
// Tap loop is `#pragma unroll 1` to keep liveness ~50 VGPRs (R2/R3 spilled at
// 256 VGPRs because full 144-way unroll + load hoisting exploded the live set).
__global__ __launch_bounds__(256, 4) void lstm_step_kernel(
    const float* __restrict__ pooled,   // [128,56,56,16]
    const float* __restrict__ h_in,     // [8,54,54,16]
    float* __restrict__ h_out,          // [8,54,54,16]
    float* __restrict__ cst,            // [8,54,54,16]
    const float* __restrict__ wpack,    // [16][9][16][8]
    const float* __restrict__ bias,     // [64]
    int t)
{
    int ch = blockIdx.y;                // wave-uniform channel

    // Stage this channel's weight slice into LDS (288 float4 = 4608 B).
    __shared__ float4 wlds[288];
    {
        const float4* src = (const float4*)(wpack + ch * 1152);
        for (int i = threadIdx.x; i < 288; i += 256) wlds[i] = src[i];
    }
    __syncthreads();                    // before any thread can exit

    int pix = blockIdx.x * 256 + threadIdx.x;
    if (pix >= NPIX) return;

    int b  = pix / (HO*WO);
    int r  = pix % (HO*WO);
    int oh = r / WO, ow = r % WO;

    float acc0 = 0.f, acc1 = 0.f, acc2 = 0.f, acc3 = 0.f;

    const float* pf = pooled + (size_t)(b*TT + t) * HP * WP * 16;
    const float* hb = h_in + (size_t)b * HO * WO * 16;

    #pragma unroll 1
    for (int tap = 0; tap < 9; ++tap) {
        int ky = tap / 3;
        int kx = tap - ky * 3;
        int ph = oh + ky;               // VALID: always in range 0..55
        int pw = ow + kx;
        int hy = oh + ky - 1;           // SAME pad for recurrent conv
        int hx = ow + kx - 1;
        bool hv = (hy >= 0 && hy < HO && hx >= 0 && hx < WO);

        const float4* pp = (const float4*)(pf + ((size_t)ph * WP + pw) * 16);
        const float4* hp = (const float4*)(hb + ((size_t)hy * WO + hx) * 16);

        float a[16], h[16];
        #pragma unroll
        for (int v = 0; v < 4; ++v) {
            float4 av = pp[v];
            a[v*4+0] = av.x; a[v*4+1] = av.y; a[v*4+2] = av.z; a[v*4+3] = av.w;
            float4 hv4 = hv ? hp[v] : make_float4(0.f, 0.f, 0.f, 0.f);
            h[v*4+0] = hv4.x; h[v*4+1] = hv4.y; h[v*4+2] = hv4.z; h[v*4+3] = hv4.w;
        }

        const float4* wl = &wlds[tap * 32];
        #pragma unroll
        for (int ci = 0; ci < 16; ++ci) {
            float4 wk4 = wl[ci*2 + 0];   // broadcast (all lanes same addr)
            float4 wr4 = wl[ci*2 + 1];
            float av = a[ci], hvv = h[ci];
            acc0 += av * wk4.x + hvv * wr4.x;
            acc1 += av * wk4.y + hvv * wr4.y;
            acc2 += av * wk4.z + hvv * wr4.z;
            acc3 += av * wk4.w + hvv * wr4.w;
        }
    }

    float iv = hsig(acc0 + bias[ 0 + ch]);
    float fv = hsig(acc1 + bias[16 + ch]);
    float gv = tanhf(acc2 + bias[32 + ch]);
    float ov = hsig(acc3 + bias[48 + ch]);

    size_t base = (size_t)pix * 16 + ch;
    float cold = cst[base];
    float cn = fv * cold + iv * gv;
    cst[base] = cn;
    h_out[base] = ov * tanhf(cn);
}

// Kernel 3: spatial mean over 54x54 -> dense(16->6) -> softmax. One block per b.
__global__ __launch_bounds__(256) void head_kernel(
    const float* __restrict__ h,    // [8,54,54,16]
    const float* __restrict__ dw,   // [16,6]
    const float* __restrict__ db,   // [6]
    float* __restrict__ out)        // [8,6]
{
    int b = blockIdx.x;
    int tid = threadIdx.x;
    const float* hb = h + (size_t)b * HO * WO * 16;
    float s = 0.0f;
    for (int i = tid; i < HO*WO*16; i += 256) s += hb[i];  // stride 256 == 0 mod 16 -> fixed ch per thread
    __shared__ float red[256];
    red[tid] = s;
    __syncthreads();
    for (int st = 128; st >= 16; st >>= 1) {
        if (tid < st) red[tid] += red[tid + st];
        __syncthreads();
    }
    __shared__ float logits[8];
    if (tid < NC) {
        float l = db[tid];
        #pragma unroll
        for (int ch = 0; ch < 16; ++ch)
            l += (red[ch] * (1.0f/2916.0f)) * dw[ch*NC + tid];
        logits[tid] = l;
    }
    __syncthreads();
    if (tid < NC) {
        float m = -1e30f;
        for (int k = 0; k < NC; ++k) m = fmaxf(m, logits[k]);
        float e = expf(logits[tid] - m);
        float d = 0.0f;
        for (int k = 0; k < NC; ++k) d += expf(logits[k] - m);
        out[b*NC + tid] = e / d;
    }
}

extern "C" void kernel_launch(void* const* d_in, const int* in_sizes, int n_in,
                              void* d_out, int out_size, void* d_ws, size_t ws_size,
                              hipStream_t stream) {
    const float* x      = (const float*)d_in[0];
    const float* conv_w = (const float*)d_in[1];
    const float* conv_b = (const float*)d_in[2];
    const float* wk     = (const float*)d_in[3];
    const float* wr     = (const float*)d_in[4];
    const float* bias   = (const float*)d_in[5];
    const float* dw     = (const float*)d_in[6];
    const float* db     = (const float*)d_in[7];
    float* out = (float*)d_out;

    float* ws     = (float*)d_ws;
    float* pooled = ws;
    float* hA     = pooled + POOLED_ELEMS;
    float* hB     = hA + HSTATE_ELEMS;
    float* cbuf   = hB + HSTATE_ELEMS;
    float* wpack  = cbuf + HSTATE_ELEMS;

    // h0 = 0, c0 = 0 (ws is poisoned before every launch)
    hipMemsetAsync(hA,   0, HSTATE_ELEMS * sizeof(float), stream);
    hipMemsetAsync(cbuf, 0, HSTATE_ELEMS * sizeof(float), stream);

    repack_kernel<<<dim3(72), dim3(256), 0, stream>>>(wk, wr, wpack);
    conv_pool_kernel<<<dim3(1568), dim3(256), 0, stream>>>(x, conv_w, conv_b, pooled);

    for (int t = 0; t < TT; ++t) {
        const float* hin  = (t & 1) ? hB : hA;
        float*       hout = (t & 1) ? hA : hB;
        lstm_step_kernel<<<dim3(92, 16), dim3(256), 0, stream>>>(
            pooled, hin, hout, cbuf, wpack, bias, t);
    }
    // t=15 (odd) wrote hA
    head_kernel<<<dim3(8), dim3(256), 0, stream>>>(hA, dw, db, out);
}

// Round 6
// 912.914 us; speedup vs baseline: 40.7307x; 1.2033x over previous
//
#include <hip/hip_runtime.h>
#include <hip/hip_bf16.h>
#include <math.h>

// Problem dims
#define BB 8
#define TT 16
#define HH 112
#define WW 112
#define CC 3
#define FF 16
#define HP 56
#define WP 56
#define HO 54
#define WO 54
#define NC 6

// ws layout (floats)
#define POOLED_ELEMS (128*56*56*16)   // 6,422,528
#define HSTATE_ELEMS (8*54*54*16)     // 373,248
#define WPACK_ELEMS  (16*9*16*8)      // 18,432  [ch][tap][ci][wk i,f,g,o | wr i,f,g,o]
#define NPIX (BB*HO*WO)               // 23328

__device__ __forceinline__ float hsig(float x) {
    return fminf(fmaxf(0.2f*x + 0.5f, 0.0f), 1.0f);
}

// Kernel 0: repack LSTM weights from [3,3,16,64] (gate-major last dim) into
// per-channel contiguous slices: wpack[ch][tap][ci][slot], slot 0..3 = wk gates
// i,f,g,o ; slot 4..7 = wr gates. One channel slice = 1152 floats = 4.6 KB,
// contiguous -> 72 scalar-cache lines (R1's layout needed 1152).
__global__ __launch_bounds__(256) void repack_kernel(
    const float* __restrict__ wk, const float* __restrict__ wr,
    float* __restrict__ wpack)
{
    int i = blockIdx.x * 256 + threadIdx.x;        // 72*256 = 18432 exact
    int slot = i & 7;
    int ci   = (i >> 3) & 15;
    int tap  = (i >> 7) % 9;
    int ch   = i / (9*16*8);
    int gate = slot & 3;
    const float* src = (slot & 4) ? wr : wk;
    wpack[i] = src[tap*16*64 + ci*64 + gate*16 + ch];
}

// Kernel 1: fused 7x7 SAME conv (3->16) + bias + relu + 2x2 maxpool.
__global__ __launch_bounds__(256) void conv_pool_kernel(
    const float* __restrict__ x,      // [128,112,112,3]
    const float* __restrict__ cw,     // [7,7,3,16]
    const float* __restrict__ cb,     // [16]
    float* __restrict__ pooled)       // [128,56,56,16]
{
    int idx = blockIdx.x * 256 + threadIdx.x;   // 128*56*56 = 401408 = 1568*256 exact
    int fr = idx / (HP*WP);
    int r  = idx % (HP*WP);
    int ph = r / WP, pw = r % WP;

    const float* xf = x + (size_t)fr * HH * WW * CC;

    float best[16];
    #pragma unroll
    for (int i = 0; i < 16; ++i) best[i] = -1e30f;

    for (int py = 0; py < 2; ++py) {
        for (int px = 0; px < 2; ++px) {
            int oh = 2*ph + py, ow = 2*pw + px;
            float acc[16];
            #pragma unroll
            for (int i = 0; i < 16; ++i) acc[i] = cb[i];
            for (int ky = 0; ky < 7; ++ky) {
                int ih = oh - 3 + ky;
                if (ih < 0 || ih >= HH) continue;
                for (int kx = 0; kx < 7; ++kx) {
                    int iw = ow - 3 + kx;
                    if (iw < 0 || iw >= WW) continue;
                    const float* xp = xf + ((size_t)ih * WW + iw) * CC;
                    const float* wp = cw + ((ky*7 + kx) * CC) * 16;
                    #pragma unroll
                    for (int ci = 0; ci < 3; ++ci) {
                        float a = xp[ci];
                        #pragma unroll
                        for (int fo = 0; fo < 16; ++fo)
                            acc[fo] += a * wp[ci*16 + fo];
                    }
                }
            }
            #pragma unroll
            for (int i = 0; i < 16; ++i) best[i] = fmaxf(best[i], acc[i]);
        }
    }

    float4* op = (float4*)(pooled + (size_t)idx * 16);
    #pragma unroll
    for (int v = 0; v < 4; ++v) {
        float4 o;
        o.x = fmaxf(best[v*4+0], 0.0f);
        o.y = fmaxf(best[v*4+1], 0.0f);
        o.z = fmaxf(best[v*4+2], 0.0f);
        o.w = fmaxf(best[v*4+3], 0.0f);
        op[v] = o;
    }
}

// Kernel 2: one ConvLSTM time step, fully fused.
// Thread = one output pixel x ONE feature channel.
// Weights ride the SCALAR pipe: ch = blockIdx.y is wave-uniform, the repacked
// slice is contiguous, inner offsets are compile-time -> s_load_dwordx16
// batches. (R4 was DS-throughput-bound: 288 broadcast ds_read_b128/thread
// ~28 us/step on the per-CU DS unit. R1 was scalar too but its layout put
// every weight dword on its own cache line.)
// Tap loop `unroll 1` (R2/R3 spill lesson); ci loop chunked x8 so <=64 weight
// SGPRs are live at once.
__global__ __launch_bounds__(256, 4) void lstm_step_kernel(
    const float* __restrict__ pooled,   // [128,56,56,16]
    const float* __restrict__ h_in,     // [8,54,54,16]
    float* __restrict__ h_out,          // [8,54,54,16]
    float* __restrict__ cst,            // [8,54,54,16]
    const float* __restrict__ wpack,    // [16][9][16][8]
    const float* __restrict__ bias,     // [64]
    int t)
{
    int ch = blockIdx.y;                // wave-uniform channel
    const float* wch = wpack + ch * 1152;

    int pix = blockIdx.x * 256 + threadIdx.x;
    if (pix >= NPIX) return;

    int b  = pix / (HO*WO);
    int r  = pix % (HO*WO);
    int oh = r / WO, ow = r % WO;

    float acc0 = 0.f, acc1 = 0.f, acc2 = 0.f, acc3 = 0.f;

    const float* pf = pooled + (size_t)(b*TT + t) * HP * WP * 16;
    const float* hb = h_in + (size_t)b * HO * WO * 16;

    #pragma unroll 1
    for (int tap = 0; tap < 9; ++tap) {
        int ky = tap / 3;
        int kx = tap - ky * 3;
        int ph = oh + ky;               // VALID: always in range 0..55
        int pw = ow + kx;
        int hy = oh + ky - 1;           // SAME pad for recurrent conv
        int hx = ow + kx - 1;
        bool hv = (hy >= 0 && hy < HO && hx >= 0 && hx < WO);

        const float4* pp = (const float4*)(pf + ((size_t)ph * WP + pw) * 16);
        const float4* hp = (const float4*)(hb + ((size_t)hy * WO + hx) * 16);

        float a[16], h[16];
        #pragma unroll
        for (int v = 0; v < 4; ++v) {
            float4 av = pp[v];
            a[v*4+0] = av.x; a[v*4+1] = av.y; a[v*4+2] = av.z; a[v*4+3] = av.w;
            float4 hv4 = hv ? hp[v] : make_float4(0.f, 0.f, 0.f, 0.f);
            h[v*4+0] = hv4.x; h[v*4+1] = hv4.y; h[v*4+2] = hv4.z; h[v*4+3] = hv4.w;
        }

        const float* wt = wch + tap * 128;   // 128 contiguous floats for this tap
        #pragma unroll 1
        for (int half = 0; half < 2; ++half) {   // ci chunks of 8 -> <=64 SGPRs live
            const float* wc = wt + half * 64;
            #pragma unroll
            for (int u = 0; u < 8; ++u) {
                int ci = half * 8 + u;
                float av = a[ci], hvv = h[ci];
                acc0 += av * wc[u*8+0] + hvv * wc[u*8+4];
                acc1 += av * wc[u*8+1] + hvv * wc[u*8+5];
                acc2 += av * wc[u*8+2] + hvv * wc[u*8+6];
                acc3 += av * wc[u*8+3] + hvv * wc[u*8+7];
            }
        }
    }

    float iv = hsig(acc0 + bias[ 0 + ch]);
    float fv = hsig(acc1 + bias[16 + ch]);
    float gv = tanhf(acc2 + bias[32 + ch]);
    float ov = hsig(acc3 + bias[48 + ch]);

    size_t base = (size_t)pix * 16 + ch;
    float cold = cst[base];
    float cn = fv * cold + iv * gv;
    cst[base] = cn;
    h_out[base] = ov * tanhf(cn);
}

// Kernel 3: spatial mean over 54x54 -> dense(16->6) -> softmax. One block per b.
__global__ __launch_bounds__(256) void head_kernel(
    const float* __restrict__ h,    // [8,54,54,16]
    const float* __restrict__ dw,   // [16,6]
    const float* __restrict__ db,   // [6]
    float* __restrict__ out)        // [8,6]
{
    int b = blockIdx.x;
    int tid = threadIdx.x;
    const float* hb = h + (size_t)b * HO * WO * 16;
    float s = 0.0f;
    for (int i = tid; i < HO*WO*16; i += 256) s += hb[i];  // stride 256 == 0 mod 16 -> fixed ch per thread
    __shared__ float red[256];
    red[tid] = s;
    __syncthreads();
    for (int st = 128; st >= 16; st >>= 1) {
        if (tid < st) red[tid] += red[tid + st];
        __syncthreads();
    }
    __shared__ float logits[8];
    if (tid < NC) {
        float l = db[tid];
        #pragma unroll
        for (int ch = 0; ch < 16; ++ch)
            l += (red[ch] * (1.0f/2916.0f)) * dw[ch*NC + tid];
        logits[tid] = l;
    }
    __syncthreads();
    if (tid < NC) {
        float m = -1e30f;
        for (int k = 0; k < NC; ++k) m = fmaxf(m, logits[k]);
        float e = expf(logits[tid] - m);
        float d = 0.0f;
        for (int k = 0; k < NC; ++k) d += expf(logits[k] - m);
        out[b*NC + tid] = e / d;
    }
}

extern "C" void kernel_launch(void* const* d_in, const int* in_sizes, int n_in,
                              void* d_out, int out_size, void* d_ws, size_t ws_size,
                              hipStream_t stream) {
    const float* x      = (const float*)d_in[0];
    const float* conv_w = (const float*)d_in[1];
    const float* conv_b = (const float*)d_in[2];
    const float* wk     = (const float*)d_in[3];
    const float* wr     = (const float*)d_in[4];
    const float* bias   = (const float*)d_in[5];
    const float* dw     = (const float*)d_in[6];
    const float* db     = (const float*)d_in[7];
    float* out = (float*)d_out;

    float* ws     = (float*)d_ws;
    float* pooled = ws;
    float* hA     = pooled + POOLED_ELEMS;
    float* hB     = hA + HSTATE_ELEMS;
    float* cbuf   = hB + HSTATE_ELEMS;
    float* wpack  = cbuf + HSTATE_ELEMS;

    // h0 = 0, c0 = 0 (ws is poisoned before every launch)
    hipMemsetAsync(hA,   0, HSTATE_ELEMS * sizeof(float), stream);
    hipMemsetAsync(cbuf, 0, HSTATE_ELEMS * sizeof(float), stream);

    repack_kernel<<<dim3(72), dim3(256), 0, stream>>>(wk, wr, wpack);
    conv_pool_kernel<<<dim3(1568), dim3(256), 0, stream>>>(x, conv_w, conv_b, pooled);

    for (int t = 0; t < TT; ++t) {
        const float* hin  = (t & 1) ? hB : hA;
        float*       hout = (t & 1) ? hA : hB;
        lstm_step_kernel<<<dim3(92, 16), dim3(256), 0, stream>>>(
            pooled, hin, hout, cbuf, wpack, bias, t);
    }
    // t=15 (odd) wrote hA
    head_kernel<<<dim3(8), dim3(256), 0, stream>>>(hA, dw, db, out);
}

// Round 7
// 680.332 us; speedup vs baseline: 54.6551x; 1.3419x over previous
//
#include <hip/hip_runtime.h>
#include <hip/hip_bf16.h>
#include <math.h>

// Problem dims
#define BB 8
#define TT 16
#define HH 112
#define WW 112
#define CC 3
#define FF 16
#define HP 56
#define WP 56
#define HO 54
#define WO 54
#define NC 6

#define NPIX (BB*HO*WO)               // 23328
#define SPIX (HO*WO)                  // 2916
#define NPT  (BB*TT*SPIX)             // 373248  (b,t,pixel)

// ws layout (float offsets)
#define POOLED_ELEMS (128*56*56*16)   // 6,422,528
#define HSTATE_ELEMS (BB*SPIX*16)     // 373,248
// wpack: wkpack [4 cg][9 tap][16 ci][4 g][4 c4] = 9216, then
//        wrpack [16 ch][9 tap][16 ci][4 g]      = 9216   -> 18432 total
#define WPACK_ELEMS  18432

__device__ __forceinline__ float hsig(float x) {
    return fminf(fmaxf(0.2f*x + 0.5f, 0.0f), 1.0f);
}

// Kernel 0: repack LSTM weights for the two consumers.
__global__ __launch_bounds__(256) void repack_kernel(
    const float* __restrict__ wk, const float* __restrict__ wr,
    float* __restrict__ wpack)
{
    int i = blockIdx.x * 256 + threadIdx.x;        // 72*256 = 18432 exact
    if (i < 9216) {
        // wkpack idx = cg*2304 + tap*256 + ci*16 + g*4 + c4
        int c4  = i & 3;
        int g   = (i >> 2) & 3;
        int ci  = (i >> 4) & 15;
        int tap = (i >> 8) % 9;
        int cg  = (i >> 8) / 9;
        wpack[i] = wk[tap*16*64 + ci*64 + g*16 + (cg*4 + c4)];
    } else {
        // wrpack idx = ch*576 + tap*64 + ci*4 + g
        int j   = i - 9216;
        int g   = j & 3;
        int ci  = (j >> 2) & 15;
        int tap = (j >> 6) % 9;
        int ch  = (j >> 6) / 9;
        wpack[i] = wr[tap*16*64 + ci*64 + g*16 + ch];
    }
}

// Kernel 1: fused 7x7 SAME conv (3->16) + bias + relu + 2x2 maxpool. (unchanged)
__global__ __launch_bounds__(256) void conv_pool_kernel(
    const float* __restrict__ x,      // [128,112,112,3]
    const float* __restrict__ cw,     // [7,7,3,16]
    const float* __restrict__ cb,     // [16]
    float* __restrict__ pooled)       // [128,56,56,16]
{
    int idx = blockIdx.x * 256 + threadIdx.x;   // 401408 exact
    int fr = idx / (HP*WP);
    int r  = idx % (HP*WP);
    int ph = r / WP, pw = r % WP;

    const float* xf = x + (size_t)fr * HH * WW * CC;

    float best[16];
    #pragma unroll
    for (int i = 0; i < 16; ++i) best[i] = -1e30f;

    for (int py = 0; py < 2; ++py) {
        for (int px = 0; px < 2; ++px) {
            int oh = 2*ph + py, ow = 2*pw + px;
            float acc[16];
            #pragma unroll
            for (int i = 0; i < 16; ++i) acc[i] = cb[i];
            for (int ky = 0; ky < 7; ++ky) {
                int ih = oh - 3 + ky;
                if (ih < 0 || ih >= HH) continue;
                for (int kx = 0; kx < 7; ++kx) {
                    int iw = ow - 3 + kx;
                    if (iw < 0 || iw >= WW) continue;
                    const float* xp = xf + ((size_t)ih * WW + iw) * CC;
                    const float* wp = cw + ((ky*7 + kx) * CC) * 16;
                    #pragma unroll
                    for (int ci = 0; ci < 3; ++ci) {
                        float a = xp[ci];
                        #pragma unroll
                        for (int fo = 0; fo < 16; ++fo)
                            acc[fo] += a * wp[ci*16 + fo];
                    }
                }
            }
            #pragma unroll
            for (int i = 0; i < 16; ++i) best[i] = fmaxf(best[i], acc[i]);
        }
    }

    float4* op = (float4*)(pooled + (size_t)idx * 16);
    #pragma unroll
    for (int v = 0; v < 4; ++v) {
        float4 o;
        o.x = fmaxf(best[v*4+0], 0.0f);
        o.y = fmaxf(best[v*4+1], 0.0f);
        o.z = fmaxf(best[v*4+2], 0.0f);
        o.w = fmaxf(best[v*4+3], 0.0f);
        op[v] = o;
    }
}

// Kernel 2a: precompute zx = conv3x3 VALID (pooled -> 64 gates) for ALL t.
// Thread = one (b,t,pixel) x 4 channels (cg from blockIdx.y, wave-uniform ->
// scalar weights). 23328 waves = 91/CU -> latency fully hidden.
// Output bf16, planar [gate*16+ch][pt] so step-kernel reads are coalesced.
__global__ __launch_bounds__(256, 4) void zx_all_kernel(
    const float* __restrict__ pooled,   // [128,56,56,16]
    const float* __restrict__ wkpack,   // [cg][tap][ci][g][c4]
    __hip_bfloat16* __restrict__ zx)    // [64][373248]
{
    int cg = blockIdx.y;                // 0..3 (channels cg*4 .. cg*4+3)
    const float* wcg = wkpack + cg * 2304;

    int pt = blockIdx.x * 256 + threadIdx.x;   // 1458*256 = 373248 exact
    int b  = pt / (TT*SPIX);
    int rt = pt % (TT*SPIX);
    int tt = rt / SPIX;
    int r  = rt % SPIX;
    int oh = r / WO, ow = r % WO;

    const float* pf = pooled + (size_t)(b*TT + tt) * HP * WP * 16;

    float acc[16];                      // [c4][g]
    #pragma unroll
    for (int i = 0; i < 16; ++i) acc[i] = 0.0f;

    #pragma unroll 1
    for (int tap = 0; tap < 9; ++tap) {
        int ky = tap / 3;
        int kx = tap - ky * 3;
        const float4* pp = (const float4*)(pf + ((size_t)(oh+ky) * WP + (ow+kx)) * 16);
        float a[16];
        #pragma unroll
        for (int v = 0; v < 4; ++v) {
            float4 x4 = pp[v];
            a[v*4+0] = x4.x; a[v*4+1] = x4.y; a[v*4+2] = x4.z; a[v*4+3] = x4.w;
        }
        const float* wt = wcg + tap * 256;
        #pragma unroll 1
        for (int q = 0; q < 4; ++q) {       // ci quarters: 64 scalar floats live
            const float* wc = wt + q * 64;
            #pragma unroll
            for (int u = 0; u < 4; ++u) {
                float av = a[q*4 + u];
                #pragma unroll
                for (int g = 0; g < 4; ++g) {
                    #pragma unroll
                    for (int c4 = 0; c4 < 4; ++c4)
                        acc[c4*4 + g] += av * wc[u*16 + g*4 + c4];
                }
            }
        }
    }

    #pragma unroll
    for (int g = 0; g < 4; ++g) {
        #pragma unroll
        for (int c4 = 0; c4 < 4; ++c4) {
            size_t o = (size_t)(g*16 + cg*4 + c4) * NPT + pt;
            zx[o] = __float2bfloat16(acc[c4*4 + g]);
        }
    }
}

// Kernel 2b: one ConvLSTM step, recurrent conv only (+ precomputed zx).
// Thread = one pixel x ONE channel (proven 5832-wave structure). h-loads are
// software-pipelined with even/odd register buffers (load tap k+1 during the
// FMAs of tap k) to break the 9x(latency+compute) serial chain. Weights wr
// ride the scalar pipe (64 floats/tap, wave-uniform, K$-resident).
__global__ __launch_bounds__(256, 4) void lstm_step_kernel(
    const __hip_bfloat16* __restrict__ zx,  // [64][373248]
    const float* __restrict__ h_in,         // [8,54,54,16]
    float* __restrict__ h_out,
    float* __restrict__ cst,
    const float* __restrict__ wrpack,       // [ch][tap][ci][g] (at +9216 in wpack)
    const float* __restrict__ bias,         // [64]
    int t)
{
    int ch = blockIdx.y;
    const float* wch = wrpack + ch * 576;

    int pix = blockIdx.x * 256 + threadIdx.x;
    if (pix >= NPIX) return;

    int b  = pix / SPIX;
    int r  = pix % SPIX;
    int oh = r / WO, ow = r % WO;

    const float* hb = h_in + (size_t)b * SPIX * 16;
    size_t pt = (size_t)b * (TT*SPIX) + (size_t)t * SPIX + r;

    // issue zx loads early (used only in epilogue)
    float z0 = __bfloat162float(zx[(size_t)( 0 + ch) * NPT + pt]);
    float z1 = __bfloat162float(zx[(size_t)(16 + ch) * NPT + pt]);
    float z2 = __bfloat162float(zx[(size_t)(32 + ch) * NPT + pt]);
    float z3 = __bfloat162float(zx[(size_t)(48 + ch) * NPT + pt]);

    float acc0 = 0.f, acc1 = 0.f, acc2 = 0.f, acc3 = 0.f;
    float bufA[16], bufB[16];

    // guarded h-vector load for tap -> dst[16]
    auto loadH = [&](int tap, float* dst) {
        int ky = tap / 3;
        int kx = tap - ky * 3;
        int hy = oh + ky - 1;
        int hx = ow + kx - 1;
        bool ok = (hy >= 0) & (hy < HO) & (hx >= 0) & (hx < WO);
        const float4* hp = (const float4*)(hb + ((size_t)hy * WO + hx) * 16);
        #pragma unroll
        for (int v = 0; v < 4; ++v) {
            float4 x4 = ok ? hp[v] : make_float4(0.f, 0.f, 0.f, 0.f);
            dst[v*4+0] = x4.x; dst[v*4+1] = x4.y; dst[v*4+2] = x4.z; dst[v*4+3] = x4.w;
        }
    };
    // FMA one tap from src[16] with scalar weights (64 floats, one batch)
    auto fmaTap = [&](int tap, const float* src) {
        const float* wt = wch + tap * 64;
        #pragma unroll
        for (int ci = 0; ci < 16; ++ci) {
            float hv = src[ci];
            acc0 += hv * wt[ci*4 + 0];
            acc1 += hv * wt[ci*4 + 1];
            acc2 += hv * wt[ci*4 + 2];
            acc3 += hv * wt[ci*4 + 3];
        }
    };

    loadH(0, bufA);
    #pragma unroll 1
    for (int k = 0; k < 4; ++k) {
        loadH(2*k + 1, bufB);   // prefetch odd tap
        fmaTap(2*k, bufA);
        loadH(2*k + 2, bufA);   // prefetch next even tap (2k+2 <= 8)
        fmaTap(2*k + 1, bufB);
    }
    fmaTap(8, bufA);

    float iv = hsig(z0 + acc0 + bias[ 0 + ch]);
    float fv = hsig(z1 + acc1 + bias[16 + ch]);
    float gv = tanhf(z2 + acc2 + bias[32 + ch]);
    float ov = hsig(z3 + acc3 + bias[48 + ch]);

    size_t base = (size_t)pix * 16 + ch;
    float cold = cst[base];
    float cn = fv * cold + iv * gv;
    cst[base] = cn;
    h_out[base] = ov * tanhf(cn);
}

// Kernel 3: spatial mean over 54x54 -> dense(16->6) -> softmax. One block per b.
__global__ __launch_bounds__(256) void head_kernel(
    const float* __restrict__ h,    // [8,54,54,16]
    const float* __restrict__ dw,   // [16,6]
    const float* __restrict__ db,   // [6]
    float* __restrict__ out)        // [8,6]
{
    int b = blockIdx.x;
    int tid = threadIdx.x;
    const float* hb = h + (size_t)b * SPIX * 16;
    float s = 0.0f;
    for (int i = tid; i < SPIX*16; i += 256) s += hb[i];
    __shared__ float red[256];
    red[tid] = s;
    __syncthreads();
    for (int st = 128; st >= 16; st >>= 1) {
        if (tid < st) red[tid] += red[tid + st];
        __syncthreads();
    }
    __shared__ float logits[8];
    if (tid < NC) {
        float l = db[tid];
        #pragma unroll
        for (int ch = 0; ch < 16; ++ch)
            l += (red[ch] * (1.0f/2916.0f)) * dw[ch*NC + tid];
        logits[tid] = l;
    }
    __syncthreads();
    if (tid < NC) {
        float m = -1e30f;
        for (int k = 0; k < NC; ++k) m = fmaxf(m, logits[k]);
        float e = expf(logits[tid] - m);
        float d = 0.0f;
        for (int k = 0; k < NC; ++k) d += expf(logits[k] - m);
        out[b*NC + tid] = e / d;
    }
}

extern "C" void kernel_launch(void* const* d_in, const int* in_sizes, int n_in,
                              void* d_out, int out_size, void* d_ws, size_t ws_size,
                              hipStream_t stream) {
    const float* x      = (const float*)d_in[0];
    const float* conv_w = (const float*)d_in[1];
    const float* conv_b = (const float*)d_in[2];
    const float* wk     = (const float*)d_in[3];
    const float* wr     = (const float*)d_in[4];
    const float* bias   = (const float*)d_in[5];
    const float* dw     = (const float*)d_in[6];
    const float* db     = (const float*)d_in[7];
    float* out = (float*)d_out;

    float* ws     = (float*)d_ws;
    float* pooled = ws;                                   // 6,422,528 f
    float* hA     = pooled + POOLED_ELEMS;                //   373,248 f
    float* hB     = hA + HSTATE_ELEMS;
    float* cbuf   = hB + HSTATE_ELEMS;
    float* wpack  = cbuf + HSTATE_ELEMS;                  //    18,432 f
    __hip_bfloat16* zx = (__hip_bfloat16*)(wpack + WPACK_ELEMS); // 23.9M bf16 (47.8 MB)
    // total ws use ~= 78.2 MB

    // h0 = 0, c0 = 0 (ws is poisoned before every launch)
    hipMemsetAsync(hA,   0, HSTATE_ELEMS * sizeof(float), stream);
    hipMemsetAsync(cbuf, 0, HSTATE_ELEMS * sizeof(float), stream);

    repack_kernel<<<dim3(72), dim3(256), 0, stream>>>(wk, wr, wpack);
    conv_pool_kernel<<<dim3(1568), dim3(256), 0, stream>>>(x, conv_w, conv_b, pooled);
    zx_all_kernel<<<dim3(1458, 4), dim3(256), 0, stream>>>(pooled, wpack, zx);

    const float* wrpack = wpack + 9216;
    for (int t = 0; t < TT; ++t) {
        const float* hin  = (t & 1) ? hB : hA;
        float*       hout = (t & 1) ? hA : hB;
        lstm_step_kernel<<<dim3(92, 16), dim3(256), 0, stream>>>(
            zx, hin, hout, cbuf, wrpack, bias, t);
    }
    // t=15 (odd) wrote hA
    head_kernel<<<dim3(8), dim3(256), 0, stream>>>(hA, dw, db, out);
}

// Round 8
// 670.894 us; speedup vs baseline: 55.4240x; 1.0141x over previous
//
#include <hip/hip_runtime.h>
#include <hip/hip_bf16.h>
#include <math.h>

// Problem dims
#define BB 8
#define TT 16
#define HH 112
#define WW 112
#define CC 3
#define FF 16
#define HP 56
#define WP 56
#define HO 54
#define WO 54
#define NC 6

#define NPIX (BB*HO*WO)               // 23328
#define SPIX (HO*WO)                  // 2916
#define NPT  (BB*TT*SPIX)             // 373248  (b,t,pixel)

// ws layout (float offsets)
#define POOLED_ELEMS (128*56*56*16)   // 6,422,528
#define HSTATE_ELEMS (BB*SPIX*16)     // 373,248
// wpack: wkpack [4 cg][9 tap][16 ci][4 g][4 c4] = 9216
//        wrpack [4 cg][9 tap][16 ci][4 g][4 c4] = 9216  -> 18432 total
#define WPACK_ELEMS  18432

__device__ __forceinline__ float hsig(float x) {
    return fminf(fmaxf(0.2f*x + 0.5f, 0.0f), 1.0f);
}

// Kernel 0: repack both LSTM weight tensors into [cg][tap][ci][g][c4].
__global__ __launch_bounds__(256) void repack_kernel(
    const float* __restrict__ wk, const float* __restrict__ wr,
    float* __restrict__ wpack)
{
    int i = blockIdx.x * 256 + threadIdx.x;        // 72*256 = 18432 exact
    int idx = (i < 9216) ? i : i - 9216;
    int c4  = idx & 3;
    int g   = (idx >> 2) & 3;
    int ci  = (idx >> 4) & 15;
    int tap = (idx >> 8) % 9;
    int cg  = (idx >> 8) / 9;
    const float* src = (i < 9216) ? wk : wr;
    wpack[i] = src[tap*1024 + ci*64 + g*16 + (cg*4 + c4)];
}

// Kernel 1: fused 7x7 SAME conv (3->16) + bias + relu + 2x2 maxpool. (unchanged)
__global__ __launch_bounds__(256) void conv_pool_kernel(
    const float* __restrict__ x,      // [128,112,112,3]
    const float* __restrict__ cw,     // [7,7,3,16]
    const float* __restrict__ cb,     // [16]
    float* __restrict__ pooled)       // [128,56,56,16]
{
    int idx = blockIdx.x * 256 + threadIdx.x;   // 401408 exact
    int fr = idx / (HP*WP);
    int r  = idx % (HP*WP);
    int ph = r / WP, pw = r % WP;

    const float* xf = x + (size_t)fr * HH * WW * CC;

    float best[16];
    #pragma unroll
    for (int i = 0; i < 16; ++i) best[i] = -1e30f;

    for (int py = 0; py < 2; ++py) {
        for (int px = 0; px < 2; ++px) {
            int oh = 2*ph + py, ow = 2*pw + px;
            float acc[16];
            #pragma unroll
            for (int i = 0; i < 16; ++i) acc[i] = cb[i];
            for (int ky = 0; ky < 7; ++ky) {
                int ih = oh - 3 + ky;
                if (ih < 0 || ih >= HH) continue;
                for (int kx = 0; kx < 7; ++kx) {
                    int iw = ow - 3 + kx;
                    if (iw < 0 || iw >= WW) continue;
                    const float* xp = xf + ((size_t)ih * WW + iw) * CC;
                    const float* wp = cw + ((ky*7 + kx) * CC) * 16;
                    #pragma unroll
                    for (int ci = 0; ci < 3; ++ci) {
                        float a = xp[ci];
                        #pragma unroll
                        for (int fo = 0; fo < 16; ++fo)
                            acc[fo] += a * wp[ci*16 + fo];
                    }
                }
            }
            #pragma unroll
            for (int i = 0; i < 16; ++i) best[i] = fmaxf(best[i], acc[i]);
        }
    }

    float4* op = (float4*)(pooled + (size_t)idx * 16);
    #pragma unroll
    for (int v = 0; v < 4; ++v) {
        float4 o;
        o.x = fmaxf(best[v*4+0], 0.0f);
        o.y = fmaxf(best[v*4+1], 0.0f);
        o.z = fmaxf(best[v*4+2], 0.0f);
        o.w = fmaxf(best[v*4+3], 0.0f);
        op[v] = o;
    }
}

// Kernel 2a: precompute zx = conv3x3 VALID (pooled -> 64 gates) for ALL t. (unchanged)
__global__ __launch_bounds__(256, 4) void zx_all_kernel(
    const float* __restrict__ pooled,   // [128,56,56,16]
    const float* __restrict__ wkpack,   // [cg][tap][ci][g][c4]
    __hip_bfloat16* __restrict__ zx)    // [64][373248]
{
    int cg = blockIdx.y;                // 0..3 (channels cg*4 .. cg*4+3)
    const float* wcg = wkpack + cg * 2304;

    int pt = blockIdx.x * 256 + threadIdx.x;   // 1458*256 = 373248 exact
    int b  = pt / (TT*SPIX);
    int rt = pt % (TT*SPIX);
    int tt = rt / SPIX;
    int r  = rt % SPIX;
    int oh = r / WO, ow = r % WO;

    const float* pf = pooled + (size_t)(b*TT + tt) * HP * WP * 16;

    float acc[16];                      // [c4][g]
    #pragma unroll
    for (int i = 0; i < 16; ++i) acc[i] = 0.0f;

    #pragma unroll 1
    for (int tap = 0; tap < 9; ++tap) {
        int ky = tap / 3;
        int kx = tap - ky * 3;
        const float4* pp = (const float4*)(pf + ((size_t)(oh+ky) * WP + (ow+kx)) * 16);
        float a[16];
        #pragma unroll
        for (int v = 0; v < 4; ++v) {
            float4 x4 = pp[v];
            a[v*4+0] = x4.x; a[v*4+1] = x4.y; a[v*4+2] = x4.z; a[v*4+3] = x4.w;
        }
        const float* wt = wcg + tap * 256;
        #pragma unroll 1
        for (int q = 0; q < 4; ++q) {       // ci quarters: 64 scalar floats live
            const float* wc = wt + q * 64;
            #pragma unroll
            for (int u = 0; u < 4; ++u) {
                float av = a[q*4 + u];
                #pragma unroll
                for (int g = 0; g < 4; ++g) {
                    #pragma unroll
                    for (int c4 = 0; c4 < 4; ++c4)
                        acc[c4*4 + g] += av * wc[u*16 + g*4 + c4];
                }
            }
        }
    }

    #pragma unroll
    for (int g = 0; g < 4; ++g) {
        #pragma unroll
        for (int c4 = 0; c4 < 4; ++c4) {
            size_t o = (size_t)(g*16 + cg*4 + c4) * NPT + pt;
            zx[o] = __float2bfloat16(acc[c4*4 + g]);
        }
    }
}

// Kernel 2b: one ConvLSTM step, recurrent conv from an LDS-staged h tile.
// Block = 18x14 pixel tile x 4-channel group (blockIdx.z = cg, wave-uniform
// -> scalar weights). Stage 20x16-pixel halo (20.5 KB) into LDS once; each
// thread then does 36 ds_read_b128 (adjacent lanes 64B apart = 2-way bank
// aliasing, free per m136). Kills the 16x L1 activation redundancy of the
// per-(pixel,ch) layout. Grid (12, 8, 4) = 384 blocks.
__global__ __launch_bounds__(256, 4) void lstm_step_kernel(
    const __hip_bfloat16* __restrict__ zx,  // [64][373248]
    const float* __restrict__ h_in,         // [8,54,54,16]
    float* __restrict__ h_out,
    float* __restrict__ cst,
    const float* __restrict__ wrpack,       // [cg][tap][ci][g][c4]
    const float* __restrict__ bias,         // [64]
    int t)
{
    int tileid = blockIdx.x;      // 0..11
    int tx = tileid % 3;          // 3 tiles x 18 cols = 54 exact
    int ty = tileid / 3;          // 4 tiles x 14 rows (covers 56, top 2 idle)
    int b  = blockIdx.y;
    int cg = blockIdx.z;
    const float* wcg = wrpack + cg * 2304;

    int tid = threadIdx.x;
    int lx = tid % 18, ly = tid / 18;   // ly 0..14 (tid<252)
    int gx = tx*18 + lx;                // 0..53 always
    int gy = ty*14 + ly;
    bool active = (tid < 252) && (gy < HO);

    const float* hb = h_in + (size_t)b * SPIX * 16;

    // zx loads issued early (consumed only in epilogue)
    int r = gy * WO + gx;
    size_t pt = (size_t)b * (TT*SPIX) + (size_t)t * SPIX + r;
    float z[16];                        // [g][c4]
    if (active) {
        #pragma unroll
        for (int g = 0; g < 4; ++g)
            #pragma unroll
            for (int c4 = 0; c4 < 4; ++c4)
                z[g*4 + c4] = __bfloat162float(zx[(size_t)(g*16 + cg*4 + c4) * NPT + pt]);
    }

    // Stage h halo tile: rows gy0-1..gy0+14 (16), cols gx0-1..gx0+18 (20).
    __shared__ float htile[320*16];     // 20.5 KB
    {
        int gy0 = ty*14 - 1, gx0 = tx*18 - 1;
        for (int i = tid; i < 320; i += 256) {
            int iy = i / 20, ix = i % 20;
            int hy = gy0 + iy, hx = gx0 + ix;
            bool ok = (hy >= 0) & (hy < HO) & (hx >= 0) & (hx < WO);
            float4* dst = (float4*)&htile[i*16];
            const float4* src = (const float4*)(hb + ((size_t)hy * WO + hx) * 16);
            #pragma unroll
            for (int v = 0; v < 4; ++v)
                dst[v] = ok ? src[v] : make_float4(0.f, 0.f, 0.f, 0.f);
        }
    }
    __syncthreads();

    if (!active) return;

    float acc[16];                      // [c4][g]
    #pragma unroll
    for (int i = 0; i < 16; ++i) acc[i] = 0.0f;

    #pragma unroll 1
    for (int tap = 0; tap < 9; ++tap) {
        int ky = tap / 3;
        int kx = tap - ky * 3;
        const float4* hp4 = (const float4*)&htile[((ly + ky)*20 + (lx + kx))*16];
        float h[16];
        #pragma unroll
        for (int v = 0; v < 4; ++v) {
            float4 t4 = hp4[v];
            h[v*4+0] = t4.x; h[v*4+1] = t4.y; h[v*4+2] = t4.z; h[v*4+3] = t4.w;
        }
        const float* wt = wcg + tap * 256;
        #pragma unroll 1
        for (int q = 0; q < 4; ++q) {   // ci quarters: 64 scalar floats live
            const float* wc = wt + q * 64;
            #pragma unroll
            for (int u = 0; u < 4; ++u) {
                float hv = h[q*4 + u];
                #pragma unroll
                for (int g = 0; g < 4; ++g) {
                    #pragma unroll
                    for (int c4 = 0; c4 < 4; ++c4)
                        acc[c4*4 + g] += hv * wc[u*16 + g*4 + c4];
                }
            }
        }
    }

    size_t base = ((size_t)(b * SPIX + r)) * 16 + cg*4;
    float4 cold4 = *(float4*)&cst[base];
    float* cold = &cold4.x;
    float4 cnew4, hnew4;
    float* cn4 = &cnew4.x; float* hn4 = &hnew4.x;
    #pragma unroll
    for (int c4 = 0; c4 < 4; ++c4) {
        int ch = cg*4 + c4;
        float iv = hsig(z[0*4+c4] + acc[c4*4+0] + bias[ 0 + ch]);
        float fv = hsig(z[1*4+c4] + acc[c4*4+1] + bias[16 + ch]);
        float gv = tanhf(z[2*4+c4] + acc[c4*4+2] + bias[32 + ch]);
        float ov = hsig(z[3*4+c4] + acc[c4*4+3] + bias[48 + ch]);
        float cn = fv * cold[c4] + iv * gv;
        cn4[c4] = cn;
        hn4[c4] = ov * tanhf(cn);
    }
    *(float4*)&cst[base] = cnew4;
    *(float4*)&h_out[base] = hnew4;
}

// Kernel 3: spatial mean over 54x54 -> dense(16->6) -> softmax. One block per b.
__global__ __launch_bounds__(256) void head_kernel(
    const float* __restrict__ h,    // [8,54,54,16]
    const float* __restrict__ dw,   // [16,6]
    const float* __restrict__ db,   // [6]
    float* __restrict__ out)        // [8,6]
{
    int b = blockIdx.x;
    int tid = threadIdx.x;
    const float* hb = h + (size_t)b * SPIX * 16;
    float s = 0.0f;
    for (int i = tid; i < SPIX*16; i += 256) s += hb[i];
    __shared__ float red[256];
    red[tid] = s;
    __syncthreads();
    for (int st = 128; st >= 16; st >>= 1) {
        if (tid < st) red[tid] += red[tid + st];
        __syncthreads();
    }
    __shared__ float logits[8];
    if (tid < NC) {
        float l = db[tid];
        #pragma unroll
        for (int ch = 0; ch < 16; ++ch)
            l += (red[ch] * (1.0f/2916.0f)) * dw[ch*NC + tid];
        logits[tid] = l;
    }
    __syncthreads();
    if (tid < NC) {
        float m = -1e30f;
        for (int k = 0; k < NC; ++k) m = fmaxf(m, logits[k]);
        float e = expf(logits[tid] - m);
        float d = 0.0f;
        for (int k = 0; k < NC; ++k) d += expf(logits[k] - m);
        out[b*NC + tid] = e / d;
    }
}

extern "C" void kernel_launch(void* const* d_in, const int* in_sizes, int n_in,
                              void* d_out, int out_size, void* d_ws, size_t ws_size,
                              hipStream_t stream) {
    const float* x      = (const float*)d_in[0];
    const float* conv_w = (const float*)d_in[1];
    const float* conv_b = (const float*)d_in[2];
    const float* wk     = (const float*)d_in[3];
    const float* wr     = (const float*)d_in[4];
    const float* bias   = (const float*)d_in[5];
    const float* dw     = (const float*)d_in[6];
    const float* db     = (const float*)d_in[7];
    float* out = (float*)d_out;

    float* ws     = (float*)d_ws;
    float* pooled = ws;                                   // 6,422,528 f
    float* hA     = pooled + POOLED_ELEMS;                //   373,248 f
    float* hB     = hA + HSTATE_ELEMS;
    float* cbuf   = hB + HSTATE_ELEMS;
    float* wpack  = cbuf + HSTATE_ELEMS;                  //    18,432 f
    __hip_bfloat16* zx = (__hip_bfloat16*)(wpack + WPACK_ELEMS); // 47.8 MB

    // h0 = 0, c0 = 0 (ws is poisoned before every launch)
    hipMemsetAsync(hA,   0, HSTATE_ELEMS * sizeof(float), stream);
    hipMemsetAsync(cbuf, 0, HSTATE_ELEMS * sizeof(float), stream);

    repack_kernel<<<dim3(72), dim3(256), 0, stream>>>(wk, wr, wpack);
    conv_pool_kernel<<<dim3(1568), dim3(256), 0, stream>>>(x, conv_w, conv_b, pooled);
    zx_all_kernel<<<dim3(1458, 4), dim3(256), 0, stream>>>(pooled, wpack, zx);

    const float* wrpack = wpack + 9216;
    for (int t = 0; t < TT; ++t) {
        const float* hin  = (t & 1) ? hB : hA;
        float*       hout = (t & 1) ? hA : hB;
        lstm_step_kernel<<<dim3(12, 8, 4), dim3(256), 0, stream>>>(
            zx, hin, hout, cbuf, wrpack, bias, t);
    }
    // t=15 (odd) wrote hA
    head_kernel<<<dim3(8), dim3(256), 0, stream>>>(hA, dw, db, out);
}